// Round 1
// baseline (2102.597 us; speedup 1.0000x reference)
//
#include <hip/hip_runtime.h>
#include <hip/hip_bf16.h>

typedef float f32x4 __attribute__((ext_vector_type(4)));
typedef short s16x8 __attribute__((ext_vector_type(8)));

#define EPS 1e-5f

__device__ __forceinline__ unsigned short f32_to_bf16_rne(float f) {
    unsigned u = __float_as_uint(f);
    unsigned r = u + 0x7FFFu + ((u >> 16) & 1u);
    return (unsigned short)(r >> 16);
}

__device__ __forceinline__ unsigned pk2(float a, float b) {
    return (unsigned)f32_to_bf16_rne(a) | ((unsigned)f32_to_bf16_rne(b) << 16);
}

__device__ __forceinline__ float bf2f(short s) {
    return __uint_as_float(((unsigned)(unsigned short)s) << 16);
}

__device__ __forceinline__ s16x8 sub8(s16x8 a, s16x8 b) {
    s16x8 r;
#pragma unroll
    for (int i = 0; i < 8; ++i) {
        r[i] = (short)f32_to_bf16_rne(bf2f(a[i]) - bf2f(b[i]));
    }
    return r;
}

// ---------------- weight packing: W[K][64] f32 -> A-frag-ordered bf16 ----------------
// frag (kc, mt): lane holds A[row=lane&15][k=8*(lane>>4)+j] of tile
//   A = W^T tile: A[row][k] = W[kc*32 + 8*(lane>>4)+j][mt*16 + (lane&15)]
// layouts: pW1a [4][4][64][8] @0, pW1b [2][4][64][8] @8192,
//          pW2a @12288, pW2b @20480  (ushort elements)
__global__ void pack_all(const float* __restrict__ W1a, const float* __restrict__ W1b,
                         const float* __restrict__ W2a, const float* __restrict__ W2b,
                         unsigned short* __restrict__ p) {
    int idx = blockIdx.x * 256 + threadIdx.x;
    const float* W;
    int off;
    if (idx < 8192) { W = W1a; off = 0; }
    else if (idx < 12288) { W = W1b; off = 8192; }
    else if (idx < 20480) { W = W2a; off = 12288; }
    else if (idx < 24576) { W = W2b; off = 20480; }
    else return;
    int t = idx - off;
    int j = t & 7;
    int lane = (t >> 3) & 63;
    int mt = (t >> 9) & 3;
    int kc = t >> 11;
    int k = kc * 32 + (lane >> 4) * 8 + j;
    int c = mt * 16 + (lane & 15);
    p[idx] = f32_to_bf16_rne(W[k * 64 + c]);
}

// ---------------- f32 -> bf16 table convert ----------------
__global__ void cvt_f32_bf16(const float* __restrict__ in, unsigned short* __restrict__ out, int n4) {
    int i = blockIdx.x * 256 + threadIdx.x;
    if (i >= n4) return;
    f32x4 v = ((const f32x4*)in)[i];
    uint2 pr;
    pr.x = pk2(v[0], v[1]);
    pr.y = pk2(v[2], v[3]);
    *(uint2*)(out + i * 4) = pr;
}

// ---------------- fused EdgeConv (MLP + segment-max via atomicMax) ----------------
// transposed scheme: D[ch][edge] = sum_k W^T[ch][k] * u^T[k][edge]
// B-frag lane: col=lane&15=edge r, k=8g+j  -> u[edge][k] = 16B load from feature row
__global__ __launch_bounds__(256) void edgeconv(
    const unsigned short* __restrict__ xb,   // [N][64] bf16 features
    const int* __restrict__ esrc,
    const int* __restrict__ edst,
    const unsigned short* __restrict__ pWa,  // packed [4][4][64][8]
    const unsigned short* __restrict__ pWb,  // packed [2][4][64][8]
    const float* __restrict__ ba,
    const float* __restrict__ bb,
    float* __restrict__ out,                 // [N][64] f32, pre-zeroed
    int E) {
    __shared__ __align__(16) unsigned short h1lds[4][16 * 72];
    const int tid = threadIdx.x;
    const int w = tid >> 6;
    const int lane = tid & 63;
    const int g = lane >> 4;
    const int r = lane & 15;

    // weight fragments in registers
    s16x8 a1[4][4], a2[2][4];
#pragma unroll
    for (int kc = 0; kc < 4; ++kc)
#pragma unroll
        for (int mt = 0; mt < 4; ++mt)
            a1[kc][mt] = *(const s16x8*)(pWa + ((kc * 4 + mt) * 64 + lane) * 8);
#pragma unroll
    for (int kc = 0; kc < 2; ++kc)
#pragma unroll
        for (int mt = 0; mt < 4; ++mt)
            a2[kc][mt] = *(const s16x8*)(pWb + ((kc * 4 + mt) * 64 + lane) * 8);

    f32x4 bias1[4], bias2[4];
#pragma unroll
    for (int mt = 0; mt < 4; ++mt) {
        bias1[mt] = *(const f32x4*)(ba + mt * 16 + g * 4);
        bias2[mt] = *(const f32x4*)(bb + mt * 16 + g * 4);
    }

    unsigned short* myl = h1lds[w];
    const int ntiles = (E + 15) >> 4;
    for (int tile = blockIdx.x * 4 + w; tile < ntiles; tile += gridDim.x * 4) {
        int e = tile * 16 + r;
        bool valid = e < E;
        int ec = valid ? e : (E - 1);
        int s = esrc[ec];
        int d = edst[ec];

        s16x8 xi1 = *(const s16x8*)(xb + d * 64 + g * 8);
        s16x8 xi2 = *(const s16x8*)(xb + d * 64 + 32 + g * 8);
        s16x8 xj1 = *(const s16x8*)(xb + s * 64 + g * 8);
        s16x8 xj2 = *(const s16x8*)(xb + s * 64 + 32 + g * 8);

        s16x8 bf0 = xi1;
        s16x8 bf1 = xi2;
        s16x8 bf2 = sub8(xj1, xi1);
        s16x8 bf3 = sub8(xj2, xi2);

        f32x4 acc[4];
#pragma unroll
        for (int mt = 0; mt < 4; ++mt) acc[mt] = (f32x4){0.f, 0.f, 0.f, 0.f};
#pragma unroll
        for (int mt = 0; mt < 4; ++mt) {
            acc[mt] = __builtin_amdgcn_mfma_f32_16x16x32_bf16(a1[0][mt], bf0, acc[mt], 0, 0, 0);
            acc[mt] = __builtin_amdgcn_mfma_f32_16x16x32_bf16(a1[1][mt], bf1, acc[mt], 0, 0, 0);
            acc[mt] = __builtin_amdgcn_mfma_f32_16x16x32_bf16(a1[2][mt], bf2, acc[mt], 0, 0, 0);
            acc[mt] = __builtin_amdgcn_mfma_f32_16x16x32_bf16(a1[3][mt], bf3, acc[mt], 0, 0, 0);
        }

        // epilogue 1: bias+relu, write h1[edge r][ch 16mt+4g..+3] to LDS (bf16)
#pragma unroll
        for (int mt = 0; mt < 4; ++mt) {
            float v0 = fmaxf(acc[mt][0] + bias1[mt][0], 0.f);
            float v1 = fmaxf(acc[mt][1] + bias1[mt][1], 0.f);
            float v2 = fmaxf(acc[mt][2] + bias1[mt][2], 0.f);
            float v3 = fmaxf(acc[mt][3] + bias1[mt][3], 0.f);
            uint2 pr;
            pr.x = pk2(v0, v1);
            pr.y = pk2(v2, v3);
            *(uint2*)(myl + r * 72 + mt * 16 + g * 4) = pr;
        }

        // B2 fragments: h1[edge r][8g+j + 32*kc2]
        s16x8 p0 = *(const s16x8*)(myl + r * 72 + g * 8);
        s16x8 p1 = *(const s16x8*)(myl + r * 72 + 32 + g * 8);

        f32x4 acc2[4];
#pragma unroll
        for (int mt = 0; mt < 4; ++mt) acc2[mt] = (f32x4){0.f, 0.f, 0.f, 0.f};
#pragma unroll
        for (int mt = 0; mt < 4; ++mt) {
            acc2[mt] = __builtin_amdgcn_mfma_f32_16x16x32_bf16(a2[0][mt], p0, acc2[mt], 0, 0, 0);
            acc2[mt] = __builtin_amdgcn_mfma_f32_16x16x32_bf16(a2[1][mt], p1, acc2[mt], 0, 0, 0);
        }

        if (valid) {
            unsigned* orow = (unsigned*)(out + d * 64);
#pragma unroll
            for (int mt = 0; mt < 4; ++mt) {
                int chb = mt * 16 + g * 4;
#pragma unroll
                for (int q = 0; q < 4; ++q) {
                    float v = fmaxf(acc2[mt][q] + bias2[mt][q], 0.f);
                    unsigned bits = __float_as_uint(v);
                    // relu >=0 -> uint order == float order; init is 0; stale read only skips safely
                    if (bits > orow[chb + q]) atomicMax(orow + chb + q, bits);
                }
            }
        }
    }
}

// ---------------- batchnorm stats: per-channel sum & sumsq ----------------
__global__ void bn_stats(const float* __restrict__ in, float* __restrict__ stats, int N) {
    __shared__ float ls[4][64];
    __shared__ float lss[4][64];
    int c = threadIdx.x & 63;
    int rg = threadIdx.x >> 6;
    float s = 0.f, ss = 0.f;
    for (int row = blockIdx.x * 4 + rg; row < N; row += gridDim.x * 4) {
        float v = in[row * 64 + c];
        s += v;
        ss += v * v;
    }
    ls[rg][c] = s;
    lss[rg][c] = ss;
    __syncthreads();
    if (rg == 0) {
        s = ls[0][c] + ls[1][c] + ls[2][c] + ls[3][c];
        ss = lss[0][c] + lss[1][c] + lss[2][c] + lss[3][c];
        atomicAdd(&stats[c], s);
        atomicAdd(&stats[64 + c], ss);
    }
}

// ---------------- batchnorm apply (optionally emit bf16 table for next layer) ----------------
__global__ void bn_apply(const float* __restrict__ in, const float* __restrict__ stats,
                         const float* __restrict__ gamma, const float* __restrict__ beta,
                         unsigned short* __restrict__ outb, float* __restrict__ outf,
                         int n4, float invN) {
    int i = blockIdx.x * 256 + threadIdx.x;
    if (i >= n4) return;
    int c0 = (i * 4) & 63;
    f32x4 v = ((const f32x4*)in)[i];
    f32x4 o;
#pragma unroll
    for (int q = 0; q < 4; ++q) {
        int c = c0 + q;
        float mean = stats[c] * invN;
        float var = stats[64 + c] * invN - mean * mean;
        float sc = gamma[c] * rsqrtf(var + EPS);
        o[q] = (v[q] - mean) * sc + beta[c];
    }
    if (outb) {
        uint2 pr;
        pr.x = pk2(o[0], o[1]);
        pr.y = pk2(o[2], o[3]);
        *(uint2*)(outb + i * 4) = pr;
    } else {
        ((f32x4*)outf)[i] = o;
    }
}

extern "C" void kernel_launch(void* const* d_in, const int* in_sizes, int n_in,
                              void* d_out, int out_size, void* d_ws, size_t ws_size,
                              hipStream_t stream) {
    const float* x = (const float*)d_in[0];
    const int* ei = (const int*)d_in[1];
    // d_in[2] = batch (unused, single graph)
    const float* W1a = (const float*)d_in[3];
    const float* b1a = (const float*)d_in[4];
    const float* W1b = (const float*)d_in[5];
    const float* b1b = (const float*)d_in[6];
    const float* gamma1 = (const float*)d_in[7];
    const float* beta1 = (const float*)d_in[8];
    const float* W2a = (const float*)d_in[9];
    const float* b2a = (const float*)d_in[10];
    const float* W2b = (const float*)d_in[11];
    const float* b2b = (const float*)d_in[12];
    const float* gamma2 = (const float*)d_in[13];
    const float* beta2 = (const float*)d_in[14];

    const int N = in_sizes[0] / 64;
    const int E = in_sizes[1] / 2;
    const int NC = N * 64;

    char* ws = (char*)d_ws;
    const size_t accBytes = (size_t)NC * 4;   // 12.8 MB
    const size_t xbBytes = (size_t)NC * 2;    // 6.4 MB
    float* acc = (float*)ws;
    unsigned short* xb = (unsigned short*)(ws + accBytes);
    unsigned short* pw = (unsigned short*)(ws + accBytes + xbBytes);
    float* stats = (float*)(ws + accBytes + xbBytes + 24576 * 2);  // 256 floats (2 layers)

    const int* esrc = ei;
    const int* edst = ei + E;

    hipMemsetAsync(acc, 0, accBytes, stream);
    hipMemsetAsync(stats, 0, 256 * 4, stream);
    hipMemsetAsync(d_out, 0, (size_t)out_size * 4, stream);

    pack_all<<<96, 256, 0, stream>>>(W1a, W1b, W2a, W2b, pw);

    int n4 = NC / 4;
    int cgrid = (n4 + 255) / 256;
    cvt_f32_bf16<<<cgrid, 256, 0, stream>>>(x, xb, n4);

    // layer 1
    edgeconv<<<1024, 256, 0, stream>>>(xb, esrc, edst, pw, pw + 8192, b1a, b1b, acc, E);
    bn_stats<<<512, 256, 0, stream>>>(acc, stats, N);
    bn_apply<<<cgrid, 256, 0, stream>>>(acc, stats, gamma1, beta1, xb, nullptr, n4, 1.0f / N);

    // layer 2
    edgeconv<<<1024, 256, 0, stream>>>(xb, esrc, edst, pw + 12288, pw + 20480, b2a, b2b,
                                       (float*)d_out, E);
    bn_stats<<<512, 256, 0, stream>>>((float*)d_out, stats + 128, N);
    bn_apply<<<cgrid, 256, 0, stream>>>((float*)d_out, stats + 128, gamma2, beta2, nullptr,
                                        (float*)d_out, n4, 1.0f / N);
}

// Round 2
// 522.075 us; speedup vs baseline: 4.0274x; 4.0274x over previous
//
#include <hip/hip_runtime.h>
#include <hip/hip_bf16.h>

typedef float f32x4 __attribute__((ext_vector_type(4)));
typedef short s16x8 __attribute__((ext_vector_type(8)));

#define EPS 1e-5f

__device__ __forceinline__ unsigned short f32_to_bf16_rne(float f) {
    unsigned u = __float_as_uint(f);
    unsigned r = u + 0x7FFFu + ((u >> 16) & 1u);
    return (unsigned short)(r >> 16);
}

__device__ __forceinline__ unsigned pk2(float a, float b) {
    return (unsigned)f32_to_bf16_rne(a) | ((unsigned)f32_to_bf16_rne(b) << 16);
}

__device__ __forceinline__ float bf2f(short s) {
    return __uint_as_float(((unsigned)(unsigned short)s) << 16);
}

__device__ __forceinline__ s16x8 sub8(s16x8 a, s16x8 b) {
    s16x8 r;
#pragma unroll
    for (int i = 0; i < 8; ++i) {
        r[i] = (short)f32_to_bf16_rne(bf2f(a[i]) - bf2f(b[i]));
    }
    return r;
}

// ---------------- weight packing: W[K][64] f32 -> A-frag-ordered bf16 ----------------
// frag (kc, mt): lane holds A[row=lane&15][k=8*(lane>>4)+j] of tile
//   A = W^T tile: A[row][k] = W[kc*32 + 8*(lane>>4)+j][mt*16 + (lane&15)]
__global__ void pack_all(const float* __restrict__ W1a, const float* __restrict__ W1b,
                         const float* __restrict__ W2a, const float* __restrict__ W2b,
                         unsigned short* __restrict__ p) {
    int idx = blockIdx.x * 256 + threadIdx.x;
    const float* W;
    int off;
    if (idx < 8192) { W = W1a; off = 0; }
    else if (idx < 12288) { W = W1b; off = 8192; }
    else if (idx < 20480) { W = W2a; off = 12288; }
    else if (idx < 24576) { W = W2b; off = 20480; }
    else return;
    int t = idx - off;
    int j = t & 7;
    int lane = (t >> 3) & 63;
    int mt = (t >> 9) & 3;
    int kc = t >> 11;
    int k = kc * 32 + (lane >> 4) * 8 + j;
    int c = mt * 16 + (lane & 15);
    p[idx] = f32_to_bf16_rne(W[k * 64 + c]);
}

// ---------------- f32 -> bf16 table convert ----------------
__global__ void cvt_f32_bf16(const float* __restrict__ in, unsigned short* __restrict__ out, int n4) {
    int i = blockIdx.x * 256 + threadIdx.x;
    if (i >= n4) return;
    f32x4 v = ((const f32x4*)in)[i];
    uint2 pr;
    pr.x = pk2(v[0], v[1]);
    pr.y = pk2(v[2], v[3]);
    *(uint2*)(out + i * 4) = pr;
}

// ---------------- counting sort of edges by dst ----------------
__global__ void hist_kernel(const int* __restrict__ edst, int* __restrict__ count, int E) {
    int i = blockIdx.x * 256 + threadIdx.x;
    if (i < E) atomicAdd(&count[edst[i]], 1);
}

// single-block exclusive scan over N counts -> offsets[N+1]; also fills cursor
__global__ void scan_kernel(const int* __restrict__ count, int* __restrict__ offsets,
                            int* __restrict__ cursor, int N) {
    __shared__ int sdata[1024];
    int t = threadIdx.x;
    int chunk = (N + 1023) >> 10;
    int b = t * chunk;
    int e = min(b + chunk, N);
    int sum = 0;
    for (int i = b; i < e; ++i) sum += count[i];
    sdata[t] = sum;
    __syncthreads();
    for (int off = 1; off < 1024; off <<= 1) {
        int v = (t >= off) ? sdata[t - off] : 0;
        __syncthreads();
        sdata[t] += v;
        __syncthreads();
    }
    int run = sdata[t] - sum;  // exclusive base for this chunk
    for (int i = b; i < e; ++i) {
        offsets[i] = run;
        cursor[i] = run;
        run += count[i];
    }
    if (t == 1023) offsets[N] = sdata[1023];
}

__global__ void scatter_kernel(const int* __restrict__ esrc, const int* __restrict__ edst,
                               int* __restrict__ cursor, int* __restrict__ ssrc, int E) {
    int i = blockIdx.x * 256 + threadIdx.x;
    if (i < E) {
        int d = edst[i];
        int pos = atomicAdd(&cursor[d], 1);
        ssrc[pos] = esrc[i];
    }
}

// ---------------- fused EdgeConv on dst-sorted edges: one wave per node ----------------
// transposed MFMA scheme: D[ch][edge], B-frag lane: col=lane&15=edge r, k=8g+j
// running max kept in registers (init -inf); bias2+relu applied after max (monotone);
// -inf + bias -> fmax(..,0)=0 reproduces the segment_max -inf -> 0 fill for empty nodes.
__global__ __launch_bounds__(256) void edgeconv_sorted(
    const unsigned short* __restrict__ xb,   // [N][64] bf16 features
    const int* __restrict__ ssrc,            // [E] src idx sorted by dst
    const int* __restrict__ offsets,         // [N+1]
    const unsigned short* __restrict__ pWa,  // packed [4][4][64][8]
    const unsigned short* __restrict__ pWb,  // packed [2][4][64][8]
    const float* __restrict__ ba,
    const float* __restrict__ bb,
    float* __restrict__ out,                 // [N][64] f32 (fully written)
    int N) {
    __shared__ __align__(16) unsigned short h1lds[4][16 * 72];
    const int tid = threadIdx.x;
    const int w = tid >> 6;
    const int lane = tid & 63;
    const int g = lane >> 4;
    const int r = lane & 15;

    int node = blockIdx.x * 4 + w;
    if (node >= N) return;

    // weight fragments in registers
    s16x8 a1[4][4], a2[2][4];
#pragma unroll
    for (int kc = 0; kc < 4; ++kc)
#pragma unroll
        for (int mt = 0; mt < 4; ++mt)
            a1[kc][mt] = *(const s16x8*)(pWa + ((kc * 4 + mt) * 64 + lane) * 8);
#pragma unroll
    for (int kc = 0; kc < 2; ++kc)
#pragma unroll
        for (int mt = 0; mt < 4; ++mt)
            a2[kc][mt] = *(const s16x8*)(pWb + ((kc * 4 + mt) * 64 + lane) * 8);

    f32x4 bias1[4], bias2[4];
#pragma unroll
    for (int mt = 0; mt < 4; ++mt) {
        bias1[mt] = *(const f32x4*)(ba + mt * 16 + g * 4);
        bias2[mt] = *(const f32x4*)(bb + mt * 16 + g * 4);
    }

    unsigned short* myl = h1lds[w];
    const int segB = offsets[node];
    const int segE = offsets[node + 1];

    f32x4 rm[4];
#pragma unroll
    for (int mt = 0; mt < 4; ++mt) rm[mt] = (f32x4){-INFINITY, -INFINITY, -INFINITY, -INFINITY};

    if (segB < segE) {
        // this node's own feature row (constant across the segment)
        s16x8 xi1 = *(const s16x8*)(xb + node * 64 + g * 8);
        s16x8 xi2 = *(const s16x8*)(xb + node * 64 + 32 + g * 8);

        for (int t0 = segB; t0 < segE; t0 += 16) {
            int idx = t0 + r;
            bool vald = idx < segE;
            int s = vald ? ssrc[idx] : node;  // pad cols with self (masked later)

            s16x8 xj1 = *(const s16x8*)(xb + s * 64 + g * 8);
            s16x8 xj2 = *(const s16x8*)(xb + s * 64 + 32 + g * 8);
            s16x8 bf2 = sub8(xj1, xi1);
            s16x8 bf3 = sub8(xj2, xi2);

            f32x4 acc[4];
#pragma unroll
            for (int mt = 0; mt < 4; ++mt) acc[mt] = (f32x4){0.f, 0.f, 0.f, 0.f};
#pragma unroll
            for (int mt = 0; mt < 4; ++mt) {
                acc[mt] = __builtin_amdgcn_mfma_f32_16x16x32_bf16(a1[0][mt], xi1, acc[mt], 0, 0, 0);
                acc[mt] = __builtin_amdgcn_mfma_f32_16x16x32_bf16(a1[1][mt], xi2, acc[mt], 0, 0, 0);
                acc[mt] = __builtin_amdgcn_mfma_f32_16x16x32_bf16(a1[2][mt], bf2, acc[mt], 0, 0, 0);
                acc[mt] = __builtin_amdgcn_mfma_f32_16x16x32_bf16(a1[3][mt], bf3, acc[mt], 0, 0, 0);
            }

            // epilogue 1: bias+relu (per-edge, feeds nonlinearity), bf16 to LDS
#pragma unroll
            for (int mt = 0; mt < 4; ++mt) {
                float v0 = fmaxf(acc[mt][0] + bias1[mt][0], 0.f);
                float v1 = fmaxf(acc[mt][1] + bias1[mt][1], 0.f);
                float v2 = fmaxf(acc[mt][2] + bias1[mt][2], 0.f);
                float v3 = fmaxf(acc[mt][3] + bias1[mt][3], 0.f);
                uint2 pr;
                pr.x = pk2(v0, v1);
                pr.y = pk2(v2, v3);
                *(uint2*)(myl + r * 72 + mt * 16 + g * 4) = pr;
            }

            s16x8 p0 = *(const s16x8*)(myl + r * 72 + g * 8);
            s16x8 p1 = *(const s16x8*)(myl + r * 72 + 32 + g * 8);

            f32x4 acc2[4];
#pragma unroll
            for (int mt = 0; mt < 4; ++mt) acc2[mt] = (f32x4){0.f, 0.f, 0.f, 0.f};
#pragma unroll
            for (int mt = 0; mt < 4; ++mt) {
                acc2[mt] = __builtin_amdgcn_mfma_f32_16x16x32_bf16(a2[0][mt], p0, acc2[mt], 0, 0, 0);
                acc2[mt] = __builtin_amdgcn_mfma_f32_16x16x32_bf16(a2[1][mt], p1, acc2[mt], 0, 0, 0);
            }

            // fold valid columns into the running max (pre-bias; bias/relu are monotone)
            if (vald) {
#pragma unroll
                for (int mt = 0; mt < 4; ++mt)
#pragma unroll
                    for (int q = 0; q < 4; ++q)
                        rm[mt][q] = fmaxf(rm[mt][q], acc2[mt][q]);
            }
        }
    }

    // butterfly max across the 16 edge-columns (lanes differing in r bits)
#pragma unroll
    for (int mt = 0; mt < 4; ++mt)
#pragma unroll
        for (int q = 0; q < 4; ++q) {
            float v = rm[mt][q];
            v = fmaxf(v, __shfl_xor(v, 1, 64));
            v = fmaxf(v, __shfl_xor(v, 2, 64));
            v = fmaxf(v, __shfl_xor(v, 4, 64));
            v = fmaxf(v, __shfl_xor(v, 8, 64));
            rm[mt][q] = v;
        }

    if (r == 0) {
#pragma unroll
        for (int mt = 0; mt < 4; ++mt) {
            f32x4 o;
#pragma unroll
            for (int q = 0; q < 4; ++q) o[q] = fmaxf(rm[mt][q] + bias2[mt][q], 0.f);
            *(f32x4*)(out + node * 64 + mt * 16 + g * 4) = o;
        }
    }
}

// ---------------- batchnorm stats: per-channel sum & sumsq ----------------
__global__ void bn_stats(const float* __restrict__ in, float* __restrict__ stats, int N) {
    __shared__ float ls[4][64];
    __shared__ float lss[4][64];
    int c = threadIdx.x & 63;
    int rg = threadIdx.x >> 6;
    float s = 0.f, ss = 0.f;
    for (int row = blockIdx.x * 4 + rg; row < N; row += gridDim.x * 4) {
        float v = in[row * 64 + c];
        s += v;
        ss += v * v;
    }
    ls[rg][c] = s;
    lss[rg][c] = ss;
    __syncthreads();
    if (rg == 0) {
        s = ls[0][c] + ls[1][c] + ls[2][c] + ls[3][c];
        ss = lss[0][c] + lss[1][c] + lss[2][c] + lss[3][c];
        atomicAdd(&stats[c], s);
        atomicAdd(&stats[64 + c], ss);
    }
}

// ---------------- batchnorm apply (optionally emit bf16 table for next layer) ----------------
__global__ void bn_apply(const float* __restrict__ in, const float* __restrict__ stats,
                         const float* __restrict__ gamma, const float* __restrict__ beta,
                         unsigned short* __restrict__ outb, float* __restrict__ outf,
                         int n4, float invN) {
    int i = blockIdx.x * 256 + threadIdx.x;
    if (i >= n4) return;
    int c0 = (i * 4) & 63;
    f32x4 v = ((const f32x4*)in)[i];
    f32x4 o;
#pragma unroll
    for (int q = 0; q < 4; ++q) {
        int c = c0 + q;
        float mean = stats[c] * invN;
        float var = stats[64 + c] * invN - mean * mean;
        float sc = gamma[c] * rsqrtf(var + EPS);
        o[q] = (v[q] - mean) * sc + beta[c];
    }
    if (outb) {
        uint2 pr;
        pr.x = pk2(o[0], o[1]);
        pr.y = pk2(o[2], o[3]);
        *(uint2*)(outb + i * 4) = pr;
    } else {
        ((f32x4*)outf)[i] = o;
    }
}

extern "C" void kernel_launch(void* const* d_in, const int* in_sizes, int n_in,
                              void* d_out, int out_size, void* d_ws, size_t ws_size,
                              hipStream_t stream) {
    const float* x = (const float*)d_in[0];
    const int* ei = (const int*)d_in[1];
    // d_in[2] = batch (unused, single graph)
    const float* W1a = (const float*)d_in[3];
    const float* b1a = (const float*)d_in[4];
    const float* W1b = (const float*)d_in[5];
    const float* b1b = (const float*)d_in[6];
    const float* gamma1 = (const float*)d_in[7];
    const float* beta1 = (const float*)d_in[8];
    const float* W2a = (const float*)d_in[9];
    const float* b2a = (const float*)d_in[10];
    const float* W2b = (const float*)d_in[11];
    const float* b2b = (const float*)d_in[12];
    const float* gamma2 = (const float*)d_in[13];
    const float* beta2 = (const float*)d_in[14];

    const int N = in_sizes[0] / 64;
    const int E = in_sizes[1] / 2;
    const int NC = N * 64;

    char* ws = (char*)d_ws;
    size_t off = 0;
    auto alloc = [&](size_t bytes) {
        char* p = ws + off;
        off += (bytes + 255) & ~(size_t)255;
        return p;
    };
    float* acc = (float*)alloc((size_t)NC * 4);            // layer-1 pre-BN output
    unsigned short* xb = (unsigned short*)alloc((size_t)NC * 2);  // bf16 feature table
    unsigned short* pw = (unsigned short*)alloc(24576 * 2);
    float* stats = (float*)alloc(256 * 4);
    int* count = (int*)alloc((size_t)N * 4);
    int* offsets = (int*)alloc((size_t)(N + 1) * 4);
    int* cursor = (int*)alloc((size_t)(N + 1) * 4);
    int* ssrc = (int*)alloc((size_t)E * 4);

    const int* esrc = ei;
    const int* edst = ei + E;

    hipMemsetAsync(stats, 0, 256 * 4, stream);
    hipMemsetAsync(count, 0, (size_t)N * 4, stream);

    pack_all<<<96, 256, 0, stream>>>(W1a, W1b, W2a, W2b, pw);

    int n4 = NC / 4;
    int cgrid = (n4 + 255) / 256;
    cvt_f32_bf16<<<cgrid, 256, 0, stream>>>(x, xb, n4);

    // counting sort of edges by dst
    int egrid = (E + 255) / 256;
    hist_kernel<<<egrid, 256, 0, stream>>>(edst, count, E);
    scan_kernel<<<1, 1024, 0, stream>>>(count, offsets, cursor, N);
    scatter_kernel<<<egrid, 256, 0, stream>>>(esrc, edst, cursor, ssrc, E);

    int ngrid = (N + 3) / 4;

    // layer 1
    edgeconv_sorted<<<ngrid, 256, 0, stream>>>(xb, ssrc, offsets, pw, pw + 8192, b1a, b1b, acc, N);
    bn_stats<<<512, 256, 0, stream>>>(acc, stats, N);
    bn_apply<<<cgrid, 256, 0, stream>>>(acc, stats, gamma1, beta1, xb, nullptr, n4, 1.0f / N);

    // layer 2
    edgeconv_sorted<<<ngrid, 256, 0, stream>>>(xb, ssrc, offsets, pw + 12288, pw + 20480, b2a, b2b,
                                               (float*)d_out, N);
    bn_stats<<<512, 256, 0, stream>>>((float*)d_out, stats + 128, N);
    bn_apply<<<cgrid, 256, 0, stream>>>((float*)d_out, stats + 128, gamma2, beta2, nullptr,
                                        (float*)d_out, n4, 1.0f / N);
}

// Round 3
// 503.848 us; speedup vs baseline: 4.1731x; 1.0362x over previous
//
#include <hip/hip_runtime.h>
#include <hip/hip_bf16.h>

typedef float f32x4 __attribute__((ext_vector_type(4)));
typedef short s16x8 __attribute__((ext_vector_type(8)));

#define EPS 1e-5f

__device__ __forceinline__ unsigned short f32_to_bf16_rne(float f) {
    unsigned u = __float_as_uint(f);
    unsigned r = u + 0x7FFFu + ((u >> 16) & 1u);
    return (unsigned short)(r >> 16);
}

__device__ __forceinline__ unsigned pk2(float a, float b) {
    return (unsigned)f32_to_bf16_rne(a) | ((unsigned)f32_to_bf16_rne(b) << 16);
}

// ---------------- weight packing + buffer zeroing ----------------
// 6 matrices, each 64x64 packed as [2][4][64][8] bf16 (4096 ushorts):
//  m=0: W1xi = W1a[0:64]-W1a[64:128]   m=1: W1xj = W1a[64:128]   m=2: W1b
//  m=3: W2xi = W2a[0:64]-W2a[64:128]   m=4: W2xj = W2a[64:128]   m=5: W2b
// frag (kc,mt): lane holds A[row=lane&15][k = kc*32 + 8*(lane>>4)+j]
__global__ void pack_all(const float* __restrict__ W1a, const float* __restrict__ W1b,
                         const float* __restrict__ W2a, const float* __restrict__ W2b,
                         unsigned short* __restrict__ p, float* __restrict__ stats,
                         int* __restrict__ count, int N) {
    int idx = blockIdx.x * 256 + threadIdx.x;
    if (idx < 24576) {
        int m = idx >> 12;
        int t = idx & 4095;
        int j = t & 7;
        int lane = (t >> 3) & 63;
        int mt = (t >> 9) & 3;
        int kc = t >> 11;
        int k = kc * 32 + (lane >> 4) * 8 + j;
        int c = mt * 16 + (lane & 15);
        float v;
        switch (m) {
            case 0: v = W1a[k * 64 + c] - W1a[(k + 64) * 64 + c]; break;
            case 1: v = W1a[(k + 64) * 64 + c]; break;
            case 2: v = W1b[k * 64 + c]; break;
            case 3: v = W2a[k * 64 + c] - W2a[(k + 64) * 64 + c]; break;
            case 4: v = W2a[(k + 64) * 64 + c]; break;
            default: v = W2b[k * 64 + c]; break;
        }
        p[idx] = f32_to_bf16_rne(v);
    } else if (idx < 24832) {
        stats[idx - 24576] = 0.f;
    } else if (idx - 24832 < N) {
        count[idx - 24832] = 0;
    }
}

// ---------------- f32 -> bf16 table convert + dst histogram ----------------
__global__ void cvt_hist(const float* __restrict__ in, unsigned short* __restrict__ out, int n4,
                         const int* __restrict__ edst, int* __restrict__ count, int E) {
    int i = blockIdx.x * 256 + threadIdx.x;
    if (i < n4) {
        f32x4 v = ((const f32x4*)in)[i];
        uint2 pr;
        pr.x = pk2(v[0], v[1]);
        pr.y = pk2(v[2], v[3]);
        *(uint2*)(out + i * 4) = pr;
    }
    if (i < E) atomicAdd(&count[edst[i]], 1);
}

// single-block exclusive scan over N counts -> offsets[N+1]; also fills cursor
__global__ void scan_kernel(const int* __restrict__ count, int* __restrict__ offsets,
                            int* __restrict__ cursor, int N) {
    __shared__ int sdata[1024];
    int t = threadIdx.x;
    int chunk = (N + 1023) >> 10;
    int b = t * chunk;
    int e = min(b + chunk, N);
    int sum = 0;
    for (int i = b; i < e; ++i) sum += count[i];
    sdata[t] = sum;
    __syncthreads();
    for (int off = 1; off < 1024; off <<= 1) {
        int v = (t >= off) ? sdata[t - off] : 0;
        __syncthreads();
        sdata[t] += v;
        __syncthreads();
    }
    int run = sdata[t] - sum;
    for (int i = b; i < e; ++i) {
        offsets[i] = run;
        cursor[i] = run;
        run += count[i];
    }
    if (t == 1023) offsets[N] = sdata[1023];
}

__global__ void scatter_kernel(const int* __restrict__ esrc, const int* __restrict__ edst,
                               int* __restrict__ cursor, int* __restrict__ ssrc, int E) {
    int i = blockIdx.x * 256 + threadIdx.x;
    if (i < E) {
        int d = edst[i];
        int pos = atomicAdd(&cursor[d], 1);
        ssrc[pos] = esrc[i];
    }
}

// ---------------- fused EdgeConv on dst-sorted edges ----------------
// h = relu(xi@Wxi + xj@Wxj + b) computed as MFMA with C-init = bias + xi-part.
// xi-part (8 MFMA) computed once per node; per 16-edge tile only the xj-part (8 MFMA).
// Persistent waves: grid-stride over nodes; Wxj/Wb fragments live in registers.
__global__ __launch_bounds__(256, 3) void edgeconv_sorted(
    const unsigned short* __restrict__ xb,    // [N][64] bf16 features
    const int* __restrict__ ssrc,             // [E] src idx sorted by dst
    const int* __restrict__ offsets,          // [N+1]
    const unsigned short* __restrict__ pWxi,  // packed [2][4][64][8]
    const unsigned short* __restrict__ pWxj,
    const unsigned short* __restrict__ pWb,
    const float* __restrict__ ba,
    const float* __restrict__ bb,
    float* __restrict__ out,                  // [N][64] f32 (fully written)
    int N) {
    __shared__ __align__(16) unsigned short h1lds[4][16 * 72];
    const int tid = threadIdx.x;
    const int w = tid >> 6;
    const int lane = tid & 63;
    const int g = lane >> 4;
    const int r = lane & 15;

    // persistent weight fragments: xj-part of layer1 + layer2
    s16x8 axj[2][4], ab[2][4];
#pragma unroll
    for (int kc = 0; kc < 2; ++kc)
#pragma unroll
        for (int mt = 0; mt < 4; ++mt) {
            axj[kc][mt] = *(const s16x8*)(pWxj + ((kc * 4 + mt) * 64 + lane) * 8);
            ab[kc][mt] = *(const s16x8*)(pWb + ((kc * 4 + mt) * 64 + lane) * 8);
        }

    unsigned short* myl = h1lds[w];
    const int totalWaves = gridDim.x * 4;

    for (int node = blockIdx.x * 4 + w; node < N; node += totalWaves) {
        const int segB = offsets[node];
        const int segE = offsets[node + 1];

        f32x4 rm[4];
#pragma unroll
        for (int mt = 0; mt < 4; ++mt)
            rm[mt] = (f32x4){-INFINITY, -INFINITY, -INFINITY, -INFINITY};

        if (segB < segE) {
            // xi-part + bias, once per node (broadcast across the 16 columns)
            s16x8 xi1 = *(const s16x8*)(xb + node * 64 + g * 8);
            s16x8 xi2 = *(const s16x8*)(xb + node * 64 + 32 + g * 8);
            f32x4 accxi[4];
#pragma unroll
            for (int mt = 0; mt < 4; ++mt)
                accxi[mt] = *(const f32x4*)(ba + mt * 16 + g * 4);
#pragma unroll
            for (int mt = 0; mt < 4; ++mt) {
                s16x8 f0 = *(const s16x8*)(pWxi + ((0 * 4 + mt) * 64 + lane) * 8);
                accxi[mt] = __builtin_amdgcn_mfma_f32_16x16x32_bf16(f0, xi1, accxi[mt], 0, 0, 0);
                s16x8 f1 = *(const s16x8*)(pWxi + ((1 * 4 + mt) * 64 + lane) * 8);
                accxi[mt] = __builtin_amdgcn_mfma_f32_16x16x32_bf16(f1, xi2, accxi[mt], 0, 0, 0);
            }

            for (int t0 = segB; t0 < segE; t0 += 16) {
                int idx = t0 + r;
                bool vald = idx < segE;
                int s = ssrc[min(idx, segE - 1)];

                s16x8 xj1 = *(const s16x8*)(xb + s * 64 + g * 8);
                s16x8 xj2 = *(const s16x8*)(xb + s * 64 + 32 + g * 8);

                f32x4 acc[4];
#pragma unroll
                for (int mt = 0; mt < 4; ++mt) acc[mt] = accxi[mt];
#pragma unroll
                for (int mt = 0; mt < 4; ++mt) {
                    acc[mt] = __builtin_amdgcn_mfma_f32_16x16x32_bf16(axj[0][mt], xj1, acc[mt], 0, 0, 0);
                    acc[mt] = __builtin_amdgcn_mfma_f32_16x16x32_bf16(axj[1][mt], xj2, acc[mt], 0, 0, 0);
                }

                // relu + pack h1 row (bf16) to per-wave LDS
#pragma unroll
                for (int mt = 0; mt < 4; ++mt) {
                    float v0 = fmaxf(acc[mt][0], 0.f);
                    float v1 = fmaxf(acc[mt][1], 0.f);
                    float v2 = fmaxf(acc[mt][2], 0.f);
                    float v3 = fmaxf(acc[mt][3], 0.f);
                    uint2 pr;
                    pr.x = pk2(v0, v1);
                    pr.y = pk2(v2, v3);
                    *(uint2*)(myl + r * 72 + mt * 16 + g * 4) = pr;
                }

                s16x8 p0 = *(const s16x8*)(myl + r * 72 + g * 8);
                s16x8 p1 = *(const s16x8*)(myl + r * 72 + 32 + g * 8);

                f32x4 acc2[4];
#pragma unroll
                for (int mt = 0; mt < 4; ++mt) acc2[mt] = (f32x4){0.f, 0.f, 0.f, 0.f};
#pragma unroll
                for (int mt = 0; mt < 4; ++mt) {
                    acc2[mt] = __builtin_amdgcn_mfma_f32_16x16x32_bf16(ab[0][mt], p0, acc2[mt], 0, 0, 0);
                    acc2[mt] = __builtin_amdgcn_mfma_f32_16x16x32_bf16(ab[1][mt], p1, acc2[mt], 0, 0, 0);
                }

                if (vald) {
#pragma unroll
                    for (int mt = 0; mt < 4; ++mt)
#pragma unroll
                        for (int q = 0; q < 4; ++q)
                            rm[mt][q] = fmaxf(rm[mt][q], acc2[mt][q]);
                }
            }
        }

        // butterfly max across the 16 edge-columns
#pragma unroll
        for (int mt = 0; mt < 4; ++mt)
#pragma unroll
            for (int q = 0; q < 4; ++q) {
                float v = rm[mt][q];
                v = fmaxf(v, __shfl_xor(v, 1, 64));
                v = fmaxf(v, __shfl_xor(v, 2, 64));
                v = fmaxf(v, __shfl_xor(v, 4, 64));
                v = fmaxf(v, __shfl_xor(v, 8, 64));
                rm[mt][q] = v;
            }

        if (r == 0) {
#pragma unroll
            for (int mt = 0; mt < 4; ++mt) {
                f32x4 b2 = *(const f32x4*)(bb + mt * 16 + g * 4);
                f32x4 o;
#pragma unroll
                for (int q = 0; q < 4; ++q) o[q] = fmaxf(rm[mt][q] + b2[q], 0.f);
                *(f32x4*)(out + node * 64 + mt * 16 + g * 4) = o;
            }
        }
    }
}

// ---------------- batchnorm stats: per-channel sum & sumsq ----------------
__global__ void bn_stats(const float* __restrict__ in, float* __restrict__ stats, int N) {
    __shared__ float ls[4][64];
    __shared__ float lss[4][64];
    int c = threadIdx.x & 63;
    int rg = threadIdx.x >> 6;
    float s = 0.f, ss = 0.f;
    for (int row = blockIdx.x * 4 + rg; row < N; row += gridDim.x * 4) {
        float v = in[row * 64 + c];
        s += v;
        ss += v * v;
    }
    ls[rg][c] = s;
    lss[rg][c] = ss;
    __syncthreads();
    if (rg == 0) {
        s = ls[0][c] + ls[1][c] + ls[2][c] + ls[3][c];
        ss = lss[0][c] + lss[1][c] + lss[2][c] + lss[3][c];
        atomicAdd(&stats[c], s);
        atomicAdd(&stats[64 + c], ss);
    }
}

// ---------------- batchnorm apply (optionally emit bf16 table for next layer) ----------------
__global__ void bn_apply(const float* __restrict__ in, const float* __restrict__ stats,
                         const float* __restrict__ gamma, const float* __restrict__ beta,
                         unsigned short* __restrict__ outb, float* __restrict__ outf,
                         int n4, float invN) {
    int i = blockIdx.x * 256 + threadIdx.x;
    if (i >= n4) return;
    int c0 = (i * 4) & 63;
    f32x4 v = ((const f32x4*)in)[i];
    f32x4 o;
#pragma unroll
    for (int q = 0; q < 4; ++q) {
        int c = c0 + q;
        float mean = stats[c] * invN;
        float var = stats[64 + c] * invN - mean * mean;
        float sc = gamma[c] * rsqrtf(var + EPS);
        o[q] = (v[q] - mean) * sc + beta[c];
    }
    if (outb) {
        uint2 pr;
        pr.x = pk2(o[0], o[1]);
        pr.y = pk2(o[2], o[3]);
        *(uint2*)(outb + i * 4) = pr;
    } else {
        ((f32x4*)outf)[i] = o;
    }
}

extern "C" void kernel_launch(void* const* d_in, const int* in_sizes, int n_in,
                              void* d_out, int out_size, void* d_ws, size_t ws_size,
                              hipStream_t stream) {
    const float* x = (const float*)d_in[0];
    const int* ei = (const int*)d_in[1];
    // d_in[2] = batch (unused, single graph)
    const float* W1a = (const float*)d_in[3];
    const float* b1a = (const float*)d_in[4];
    const float* W1b = (const float*)d_in[5];
    const float* b1b = (const float*)d_in[6];
    const float* gamma1 = (const float*)d_in[7];
    const float* beta1 = (const float*)d_in[8];
    const float* W2a = (const float*)d_in[9];
    const float* b2a = (const float*)d_in[10];
    const float* W2b = (const float*)d_in[11];
    const float* b2b = (const float*)d_in[12];
    const float* gamma2 = (const float*)d_in[13];
    const float* beta2 = (const float*)d_in[14];

    const int N = in_sizes[0] / 64;
    const int E = in_sizes[1] / 2;
    const int NC = N * 64;

    char* ws = (char*)d_ws;
    size_t off = 0;
    auto alloc = [&](size_t bytes) {
        char* p = ws + off;
        off += (bytes + 255) & ~(size_t)255;
        return p;
    };
    float* acc = (float*)alloc((size_t)NC * 4);                   // layer-1 pre-BN output
    unsigned short* xb = (unsigned short*)alloc((size_t)NC * 2);  // bf16 feature table
    unsigned short* pw = (unsigned short*)alloc(24576 * 2);
    float* stats = (float*)alloc(256 * 4);
    int* count = (int*)alloc((size_t)N * 4);
    int* offsets = (int*)alloc((size_t)(N + 1) * 4);
    int* cursor = (int*)alloc((size_t)(N + 1) * 4);
    int* ssrc = (int*)alloc((size_t)E * 4);

    const int* esrc = ei;
    const int* edst = ei + E;

    // pack weights + zero stats/count
    int pgrid = (24832 + N + 255) / 256;
    pack_all<<<pgrid, 256, 0, stream>>>(W1a, W1b, W2a, W2b, pw, stats, count, N);

    // bf16 table + dst histogram
    int n4 = NC / 4;
    int big = max(n4, E);
    cvt_hist<<<(big + 255) / 256, 256, 0, stream>>>(x, xb, n4, edst, count, E);

    scan_kernel<<<1, 1024, 0, stream>>>(count, offsets, cursor, N);
    scatter_kernel<<<(E + 255) / 256, 256, 0, stream>>>(esrc, edst, cursor, ssrc, E);

    int cgrid = (n4 + 255) / 256;

    // layer 1
    edgeconv_sorted<<<1024, 256, 0, stream>>>(xb, ssrc, offsets, pw, pw + 4096, pw + 8192,
                                              b1a, b1b, acc, N);
    bn_stats<<<512, 256, 0, stream>>>(acc, stats, N);
    bn_apply<<<cgrid, 256, 0, stream>>>(acc, stats, gamma1, beta1, xb, nullptr, n4, 1.0f / N);

    // layer 2
    edgeconv_sorted<<<1024, 256, 0, stream>>>(xb, ssrc, offsets, pw + 12288, pw + 16384,
                                              pw + 20480, b2a, b2b, (float*)d_out, N);
    bn_stats<<<512, 256, 0, stream>>>((float*)d_out, stats + 128, N);
    bn_apply<<<cgrid, 256, 0, stream>>>((float*)d_out, stats + 128, gamma2, beta2, nullptr,
                                        (float*)d_out, n4, 1.0f / N);
}

// Round 4
// 463.184 us; speedup vs baseline: 4.5394x; 1.0878x over previous
//
#include <hip/hip_runtime.h>
#include <hip/hip_bf16.h>

typedef float f32x4 __attribute__((ext_vector_type(4)));
typedef short s16x8 __attribute__((ext_vector_type(8)));

#define EPS 1e-5f

__device__ __forceinline__ unsigned short f32_to_bf16_rne(float f) {
    unsigned u = __float_as_uint(f);
    unsigned r = u + 0x7FFFu + ((u >> 16) & 1u);
    return (unsigned short)(r >> 16);
}

__device__ __forceinline__ unsigned pk2(float a, float b) {
    return (unsigned)f32_to_bf16_rne(a) | ((unsigned)f32_to_bf16_rne(b) << 16);
}

// ---------------- weight packing + buffer zeroing ----------------
// 6 matrices, each 64x64 packed as [2][4][64][8] bf16 (4096 ushorts):
//  m=0: W1xi = W1a[0:64]-W1a[64:128]   m=1: W1xj = W1a[64:128]   m=2: W1b
//  m=3: W2xi = W2a[0:64]-W2a[64:128]   m=4: W2xj = W2a[64:128]   m=5: W2b
__global__ void pack_all(const float* __restrict__ W1a, const float* __restrict__ W1b,
                         const float* __restrict__ W2a, const float* __restrict__ W2b,
                         unsigned short* __restrict__ p, float* __restrict__ stats,
                         int* __restrict__ count, int N) {
    int idx = blockIdx.x * 256 + threadIdx.x;
    if (idx < 24576) {
        int m = idx >> 12;
        int t = idx & 4095;
        int j = t & 7;
        int lane = (t >> 3) & 63;
        int mt = (t >> 9) & 3;
        int kc = t >> 11;
        int k = kc * 32 + (lane >> 4) * 8 + j;
        int c = mt * 16 + (lane & 15);
        float v;
        switch (m) {
            case 0: v = W1a[k * 64 + c] - W1a[(k + 64) * 64 + c]; break;
            case 1: v = W1a[(k + 64) * 64 + c]; break;
            case 2: v = W1b[k * 64 + c]; break;
            case 3: v = W2a[k * 64 + c] - W2a[(k + 64) * 64 + c]; break;
            case 4: v = W2a[(k + 64) * 64 + c]; break;
            default: v = W2b[k * 64 + c]; break;
        }
        p[idx] = f32_to_bf16_rne(v);
    } else if (idx < 24832) {
        stats[idx - 24576] = 0.f;
    } else if (idx - 24832 < N) {
        count[idx - 24832] = 0;
    }
}

// ---------------- f32 -> bf16 table convert + dst histogram ----------------
__global__ void cvt_hist(const float* __restrict__ in, unsigned short* __restrict__ out, int n4,
                         const int* __restrict__ edst, int* __restrict__ count, int E) {
    int i = blockIdx.x * 256 + threadIdx.x;
    if (i < n4) {
        f32x4 v = ((const f32x4*)in)[i];
        uint2 pr;
        pr.x = pk2(v[0], v[1]);
        pr.y = pk2(v[2], v[3]);
        *(uint2*)(out + i * 4) = pr;
    }
    if (i < E) atomicAdd(&count[edst[i]], 1);
}

// single-block exclusive scan over N counts -> offsets[N+1]; also fills cursor
__global__ void scan_kernel(const int* __restrict__ count, int* __restrict__ offsets,
                            int* __restrict__ cursor, int N) {
    __shared__ int sdata[1024];
    int t = threadIdx.x;
    int chunk = (N + 1023) >> 10;
    int b = t * chunk;
    int e = min(b + chunk, N);
    int sum = 0;
    for (int i = b; i < e; ++i) sum += count[i];
    sdata[t] = sum;
    __syncthreads();
    for (int off = 1; off < 1024; off <<= 1) {
        int v = (t >= off) ? sdata[t - off] : 0;
        __syncthreads();
        sdata[t] += v;
        __syncthreads();
    }
    int run = sdata[t] - sum;
    for (int i = b; i < e; ++i) {
        offsets[i] = run;
        cursor[i] = run;
        run += count[i];
    }
    if (t == 1023) offsets[N] = sdata[1023];
}

__global__ void scatter_kernel(const int* __restrict__ esrc, const int* __restrict__ edst,
                               int* __restrict__ cursor, int* __restrict__ ssrc, int E) {
    int i = blockIdx.x * 256 + threadIdx.x;
    if (i < E) {
        int d = edst[i];
        int pos = atomicAdd(&cursor[d], 1);
        ssrc[pos] = esrc[i];
    }
}

// ---------------- fused EdgeConv on dst-sorted edges ----------------
// h = relu(xi@Wxi + xj@Wxj + b); C-init = bias + xi-part (once per node).
// Gather path: lane L loads 16B chunk (L&3) of row ssrc[t0+(L>>2)]  -> 4 adjacent
// lanes cover one 64B line (TA-coalescible), staged to per-wave LDS, then
// ds_read_b128 restores the MFMA B-fragment layout (col=lane&15, k-chunk=lane>>4).
__global__ __launch_bounds__(256, 3) void edgeconv_sorted(
    const unsigned short* __restrict__ xb,    // [N][64] bf16 features
    const int* __restrict__ ssrc,             // [E] src idx sorted by dst
    const int* __restrict__ offsets,          // [N+1]
    const unsigned short* __restrict__ pWxi,  // packed [2][4][64][8]
    const unsigned short* __restrict__ pWxj,
    const unsigned short* __restrict__ pWb,
    const float* __restrict__ ba,
    const float* __restrict__ bb,
    float* __restrict__ out,                  // [N][64] f32 (fully written)
    int N) {
    __shared__ __align__(16) unsigned short xstage[4][16 * 72];  // staged xj rows
    __shared__ __align__(16) unsigned short h1lds[4][16 * 72];   // h1 bounce
    const int tid = threadIdx.x;
    const int w = tid >> 6;
    const int lane = tid & 63;
    const int g = lane >> 4;
    const int r = lane & 15;
    const int srow = lane >> 2;   // staging: row slot this lane serves
    const int schk = lane & 3;    // staging: 16B chunk within row half

    // persistent weight fragments: xj-part of layer1 + layer2
    s16x8 axj[2][4], ab[2][4];
#pragma unroll
    for (int kc = 0; kc < 2; ++kc)
#pragma unroll
        for (int mt = 0; mt < 4; ++mt) {
            axj[kc][mt] = *(const s16x8*)(pWxj + ((kc * 4 + mt) * 64 + lane) * 8);
            ab[kc][mt] = *(const s16x8*)(pWb + ((kc * 4 + mt) * 64 + lane) * 8);
        }

    unsigned short* myx = xstage[w];
    unsigned short* myl = h1lds[w];
    const int totalWaves = gridDim.x * 4;

    for (int node = blockIdx.x * 4 + w; node < N; node += totalWaves) {
        const int segB = offsets[node];
        const int segE = offsets[node + 1];

        f32x4 rm[4];
#pragma unroll
        for (int mt = 0; mt < 4; ++mt)
            rm[mt] = (f32x4){-INFINITY, -INFINITY, -INFINITY, -INFINITY};

        if (segB < segE) {
            // xi-part + bias, once per node (broadcast across the 16 columns)
            s16x8 xi1 = *(const s16x8*)(xb + node * 64 + g * 8);
            s16x8 xi2 = *(const s16x8*)(xb + node * 64 + 32 + g * 8);
            f32x4 accxi[4];
#pragma unroll
            for (int mt = 0; mt < 4; ++mt)
                accxi[mt] = *(const f32x4*)(ba + mt * 16 + g * 4);
#pragma unroll
            for (int mt = 0; mt < 4; ++mt) {
                s16x8 f0 = *(const s16x8*)(pWxi + ((0 * 4 + mt) * 64 + lane) * 8);
                accxi[mt] = __builtin_amdgcn_mfma_f32_16x16x32_bf16(f0, xi1, accxi[mt], 0, 0, 0);
                s16x8 f1 = *(const s16x8*)(pWxi + ((1 * 4 + mt) * 64 + lane) * 8);
                accxi[mt] = __builtin_amdgcn_mfma_f32_16x16x32_bf16(f1, xi2, accxi[mt], 0, 0, 0);
            }

            for (int t0 = segB; t0 < segE; t0 += 16) {
                // coalesced gather: 4 adjacent lanes load one 64B span of a row
                int sidx = min(t0 + srow, segE - 1);
                int s = ssrc[sidx];
                s16x8 ra = *(const s16x8*)(xb + s * 64 + schk * 8);        // bytes 0..63
                s16x8 rb = *(const s16x8*)(xb + s * 64 + 32 + schk * 8);   // bytes 64..127
                *(s16x8*)(myx + srow * 72 + schk * 8) = ra;
                *(s16x8*)(myx + srow * 72 + 32 + schk * 8) = rb;
                // per-wave LDS: lockstep, no barrier needed
                s16x8 xj1 = *(const s16x8*)(myx + r * 72 + g * 8);
                s16x8 xj2 = *(const s16x8*)(myx + r * 72 + 32 + g * 8);

                f32x4 acc[4];
#pragma unroll
                for (int mt = 0; mt < 4; ++mt) acc[mt] = accxi[mt];
#pragma unroll
                for (int mt = 0; mt < 4; ++mt) {
                    acc[mt] = __builtin_amdgcn_mfma_f32_16x16x32_bf16(axj[0][mt], xj1, acc[mt], 0, 0, 0);
                    acc[mt] = __builtin_amdgcn_mfma_f32_16x16x32_bf16(axj[1][mt], xj2, acc[mt], 0, 0, 0);
                }

                // relu + pack h1 row (bf16) to per-wave LDS
#pragma unroll
                for (int mt = 0; mt < 4; ++mt) {
                    float v0 = fmaxf(acc[mt][0], 0.f);
                    float v1 = fmaxf(acc[mt][1], 0.f);
                    float v2 = fmaxf(acc[mt][2], 0.f);
                    float v3 = fmaxf(acc[mt][3], 0.f);
                    uint2 pr;
                    pr.x = pk2(v0, v1);
                    pr.y = pk2(v2, v3);
                    *(uint2*)(myl + r * 72 + mt * 16 + g * 4) = pr;
                }

                s16x8 p0 = *(const s16x8*)(myl + r * 72 + g * 8);
                s16x8 p1 = *(const s16x8*)(myl + r * 72 + 32 + g * 8);

                f32x4 acc2[4];
#pragma unroll
                for (int mt = 0; mt < 4; ++mt) acc2[mt] = (f32x4){0.f, 0.f, 0.f, 0.f};
#pragma unroll
                for (int mt = 0; mt < 4; ++mt) {
                    acc2[mt] = __builtin_amdgcn_mfma_f32_16x16x32_bf16(ab[0][mt], p0, acc2[mt], 0, 0, 0);
                    acc2[mt] = __builtin_amdgcn_mfma_f32_16x16x32_bf16(ab[1][mt], p1, acc2[mt], 0, 0, 0);
                }

                if (t0 + r < segE) {
#pragma unroll
                    for (int mt = 0; mt < 4; ++mt)
#pragma unroll
                        for (int q = 0; q < 4; ++q)
                            rm[mt][q] = fmaxf(rm[mt][q], acc2[mt][q]);
                }
            }
        }

        // butterfly max across the 16 edge-columns
#pragma unroll
        for (int mt = 0; mt < 4; ++mt)
#pragma unroll
            for (int q = 0; q < 4; ++q) {
                float v = rm[mt][q];
                v = fmaxf(v, __shfl_xor(v, 1, 64));
                v = fmaxf(v, __shfl_xor(v, 2, 64));
                v = fmaxf(v, __shfl_xor(v, 4, 64));
                v = fmaxf(v, __shfl_xor(v, 8, 64));
                rm[mt][q] = v;
            }

        if (r == 0) {
#pragma unroll
            for (int mt = 0; mt < 4; ++mt) {
                f32x4 b2 = *(const f32x4*)(bb + mt * 16 + g * 4);
                f32x4 o;
#pragma unroll
                for (int q = 0; q < 4; ++q) o[q] = fmaxf(rm[mt][q] + b2[q], 0.f);
                *(f32x4*)(out + node * 64 + mt * 16 + g * 4) = o;
            }
        }
    }
}

// ---------------- batchnorm stats: per-channel sum & sumsq ----------------
__global__ void bn_stats(const float* __restrict__ in, float* __restrict__ stats, int N) {
    __shared__ float ls[4][64];
    __shared__ float lss[4][64];
    int c = threadIdx.x & 63;
    int rg = threadIdx.x >> 6;
    float s = 0.f, ss = 0.f;
    for (int row = blockIdx.x * 4 + rg; row < N; row += gridDim.x * 4) {
        float v = in[row * 64 + c];
        s += v;
        ss += v * v;
    }
    ls[rg][c] = s;
    lss[rg][c] = ss;
    __syncthreads();
    if (rg == 0) {
        s = ls[0][c] + ls[1][c] + ls[2][c] + ls[3][c];
        ss = lss[0][c] + lss[1][c] + lss[2][c] + lss[3][c];
        atomicAdd(&stats[c], s);
        atomicAdd(&stats[64 + c], ss);
    }
}

// ---------------- batchnorm apply (optionally emit bf16 table for next layer) ----------------
__global__ void bn_apply(const float* __restrict__ in, const float* __restrict__ stats,
                         const float* __restrict__ gamma, const float* __restrict__ beta,
                         unsigned short* __restrict__ outb, float* __restrict__ outf,
                         int n4, float invN) {
    int i = blockIdx.x * 256 + threadIdx.x;
    if (i >= n4) return;
    int c0 = (i * 4) & 63;
    f32x4 v = ((const f32x4*)in)[i];
    f32x4 o;
#pragma unroll
    for (int q = 0; q < 4; ++q) {
        int c = c0 + q;
        float mean = stats[c] * invN;
        float var = stats[64 + c] * invN - mean * mean;
        float sc = gamma[c] * rsqrtf(var + EPS);
        o[q] = (v[q] - mean) * sc + beta[c];
    }
    if (outb) {
        uint2 pr;
        pr.x = pk2(o[0], o[1]);
        pr.y = pk2(o[2], o[3]);
        *(uint2*)(outb + i * 4) = pr;
    } else {
        ((f32x4*)outf)[i] = o;
    }
}

extern "C" void kernel_launch(void* const* d_in, const int* in_sizes, int n_in,
                              void* d_out, int out_size, void* d_ws, size_t ws_size,
                              hipStream_t stream) {
    const float* x = (const float*)d_in[0];
    const int* ei = (const int*)d_in[1];
    // d_in[2] = batch (unused, single graph)
    const float* W1a = (const float*)d_in[3];
    const float* b1a = (const float*)d_in[4];
    const float* W1b = (const float*)d_in[5];
    const float* b1b = (const float*)d_in[6];
    const float* gamma1 = (const float*)d_in[7];
    const float* beta1 = (const float*)d_in[8];
    const float* W2a = (const float*)d_in[9];
    const float* b2a = (const float*)d_in[10];
    const float* W2b = (const float*)d_in[11];
    const float* b2b = (const float*)d_in[12];
    const float* gamma2 = (const float*)d_in[13];
    const float* beta2 = (const float*)d_in[14];

    const int N = in_sizes[0] / 64;
    const int E = in_sizes[1] / 2;
    const int NC = N * 64;

    char* ws = (char*)d_ws;
    size_t off = 0;
    auto alloc = [&](size_t bytes) {
        char* p = ws + off;
        off += (bytes + 255) & ~(size_t)255;
        return p;
    };
    float* acc = (float*)alloc((size_t)NC * 4);                   // layer-1 pre-BN output
    unsigned short* xb = (unsigned short*)alloc((size_t)NC * 2);  // bf16 feature table
    unsigned short* pw = (unsigned short*)alloc(24576 * 2);
    float* stats = (float*)alloc(256 * 4);
    int* count = (int*)alloc((size_t)N * 4);
    int* offsets = (int*)alloc((size_t)(N + 1) * 4);
    int* cursor = (int*)alloc((size_t)(N + 1) * 4);
    int* ssrc = (int*)alloc((size_t)E * 4);

    const int* esrc = ei;
    const int* edst = ei + E;

    // pack weights + zero stats/count
    int pgrid = (24832 + N + 255) / 256;
    pack_all<<<pgrid, 256, 0, stream>>>(W1a, W1b, W2a, W2b, pw, stats, count, N);

    // bf16 table + dst histogram
    int n4 = NC / 4;
    int big = max(n4, E);
    cvt_hist<<<(big + 255) / 256, 256, 0, stream>>>(x, xb, n4, edst, count, E);

    scan_kernel<<<1, 1024, 0, stream>>>(count, offsets, cursor, N);
    scatter_kernel<<<(E + 255) / 256, 256, 0, stream>>>(esrc, edst, cursor, ssrc, E);

    int cgrid = (n4 + 255) / 256;

    // layer 1
    edgeconv_sorted<<<1024, 256, 0, stream>>>(xb, ssrc, offsets, pw, pw + 4096, pw + 8192,
                                              b1a, b1b, acc, N);
    bn_stats<<<512, 256, 0, stream>>>(acc, stats, N);
    bn_apply<<<cgrid, 256, 0, stream>>>(acc, stats, gamma1, beta1, xb, nullptr, n4, 1.0f / N);

    // layer 2
    edgeconv_sorted<<<1024, 256, 0, stream>>>(xb, ssrc, offsets, pw + 12288, pw + 16384,
                                              pw + 20480, b2a, b2b, (float*)d_out, N);
    bn_stats<<<512, 256, 0, stream>>>((float*)d_out, stats + 128, N);
    bn_apply<<<cgrid, 256, 0, stream>>>((float*)d_out, stats + 128, gamma2, beta2, nullptr,
                                        (float*)d_out, n4, 1.0f / N);
}

// Round 5
// 329.467 us; speedup vs baseline: 6.3818x; 1.4059x over previous
//
#include <hip/hip_runtime.h>
#include <hip/hip_bf16.h>

typedef float f32x4 __attribute__((ext_vector_type(4)));
typedef short s16x8 __attribute__((ext_vector_type(8)));

#define EPS 1e-5f

__device__ __forceinline__ unsigned short f32_to_bf16_rne(float f) {
    unsigned u = __float_as_uint(f);
    unsigned r = u + 0x7FFFu + ((u >> 16) & 1u);
    return (unsigned short)(r >> 16);
}

__device__ __forceinline__ unsigned pk2(float a, float b) {
    return (unsigned)f32_to_bf16_rne(a) | ((unsigned)f32_to_bf16_rne(b) << 16);
}

// ---------------- weight packing + buffer zeroing ----------------
// 6 matrices, each 64x64 packed as [2][4][64][8] bf16 (4096 ushorts):
//  m=0: W1xi = W1a[0:64]-W1a[64:128]   m=1: W1xj = W1a[64:128]   m=2: W1b
//  m=3: W2xi = W2a[0:64]-W2a[64:128]   m=4: W2xj = W2a[64:128]   m=5: W2b
__global__ void pack_all(const float* __restrict__ W1a, const float* __restrict__ W1b,
                         const float* __restrict__ W2a, const float* __restrict__ W2b,
                         unsigned short* __restrict__ p, float* __restrict__ stats,
                         int* __restrict__ count, int N) {
    int idx = blockIdx.x * 256 + threadIdx.x;
    if (idx < 24576) {
        int m = idx >> 12;
        int t = idx & 4095;
        int j = t & 7;
        int lane = (t >> 3) & 63;
        int mt = (t >> 9) & 3;
        int kc = t >> 11;
        int k = kc * 32 + (lane >> 4) * 8 + j;
        int c = mt * 16 + (lane & 15);
        float v;
        switch (m) {
            case 0: v = W1a[k * 64 + c] - W1a[(k + 64) * 64 + c]; break;
            case 1: v = W1a[(k + 64) * 64 + c]; break;
            case 2: v = W1b[k * 64 + c]; break;
            case 3: v = W2a[k * 64 + c] - W2a[(k + 64) * 64 + c]; break;
            case 4: v = W2a[(k + 64) * 64 + c]; break;
            default: v = W2b[k * 64 + c]; break;
        }
        p[idx] = f32_to_bf16_rne(v);
    } else if (idx < 24832) {
        stats[idx - 24576] = 0.f;
    } else if (idx - 24832 < N) {
        count[idx - 24832] = 0;
    }
}

// ---------------- f32 -> bf16 table convert + dst histogram ----------------
__global__ void cvt_hist(const float* __restrict__ in, unsigned short* __restrict__ out, int n4,
                         const int* __restrict__ edst, int* __restrict__ count, int E) {
    int i = blockIdx.x * 256 + threadIdx.x;
    if (i < n4) {
        f32x4 v = ((const f32x4*)in)[i];
        uint2 pr;
        pr.x = pk2(v[0], v[1]);
        pr.y = pk2(v[2], v[3]);
        *(uint2*)(out + i * 4) = pr;
    }
    if (i < E) atomicAdd(&count[edst[i]], 1);
}

// ---------------- two-level scan: 1024 elems/block ----------------
__global__ void scan1(const int* __restrict__ count, int* __restrict__ offsets,
                      int* __restrict__ bsums, int N) {
    __shared__ int sdata[256];
    int t = threadIdx.x;
    int base = blockIdx.x * 1024 + t * 4;
    int4 v = {0, 0, 0, 0};
    if (base + 3 < N) {
        v = *(const int4*)(count + base);
    } else {
        if (base + 0 < N) v.x = count[base + 0];
        if (base + 1 < N) v.y = count[base + 1];
        if (base + 2 < N) v.z = count[base + 2];
    }
    int s = v.x + v.y + v.z + v.w;
    sdata[t] = s;
    __syncthreads();
    for (int off = 1; off < 256; off <<= 1) {
        int u = (t >= off) ? sdata[t - off] : 0;
        __syncthreads();
        sdata[t] += u;
        __syncthreads();
    }
    int excl = sdata[t] - s;
    if (t == 255) bsums[blockIdx.x] = sdata[255];
    int o0 = excl;
    int o1 = o0 + v.x;
    int o2 = o1 + v.y;
    int o3 = o2 + v.z;
    if (base + 0 < N) offsets[base + 0] = o0;
    if (base + 1 < N) offsets[base + 1] = o1;
    if (base + 2 < N) offsets[base + 2] = o2;
    if (base + 3 < N) offsets[base + 3] = o3;
}

__global__ void scan2(int* __restrict__ bsums, int* __restrict__ offsets, int N, int nb) {
    __shared__ int sdata[256];
    int t = threadIdx.x;
    int s = (t < nb) ? bsums[t] : 0;
    sdata[t] = s;
    __syncthreads();
    for (int off = 1; off < 256; off <<= 1) {
        int u = (t >= off) ? sdata[t - off] : 0;
        __syncthreads();
        sdata[t] += u;
        __syncthreads();
    }
    if (t < nb) bsums[t] = sdata[t] - s;
    if (t == 255) offsets[N] = sdata[255];
}

__global__ void scan3(int* __restrict__ offsets, int* __restrict__ cursor,
                      const int* __restrict__ bsums, int N) {
    int i = blockIdx.x * 256 + threadIdx.x;
    if (i < N) {
        int v = offsets[i] + bsums[i >> 10];
        offsets[i] = v;
        cursor[i] = v;
    }
}

__global__ void scatter_kernel(const int* __restrict__ esrc, const int* __restrict__ edst,
                               int* __restrict__ cursor, int* __restrict__ ssrc, int E) {
    int i = blockIdx.x * 256 + threadIdx.x;
    if (i < E) {
        int d = edst[i];
        int pos = atomicAdd(&cursor[d], 1);
        ssrc[pos] = esrc[i];
    }
}

// ---------------- fused EdgeConv on dst-sorted edges ----------------
// h = relu(xi@Wxi + xj@Wxj + b); C-init = bias + xi-part (once per node).
// Gather path: lane L loads 16B chunk (L&3) of row ssrc[t0+(L>>2)] -> 4 adjacent
// lanes cover one 64B line, staged via per-wave LDS to the MFMA B-frag layout.
__global__ __launch_bounds__(256, 3) void edgeconv_sorted(
    const unsigned short* __restrict__ xb,    // [N][64] bf16 features
    const int* __restrict__ ssrc,             // [E] src idx sorted by dst
    const int* __restrict__ offsets,          // [N+1]
    const unsigned short* __restrict__ pWxi,  // packed [2][4][64][8]
    const unsigned short* __restrict__ pWxj,
    const unsigned short* __restrict__ pWb,
    const float* __restrict__ ba,
    const float* __restrict__ bb,
    float* __restrict__ out,                  // [N][64] f32 (fully written)
    int N) {
    __shared__ __align__(16) unsigned short xstage[4][16 * 72];  // staged xj rows
    __shared__ __align__(16) unsigned short h1lds[4][16 * 72];   // h1 bounce
    const int tid = threadIdx.x;
    const int w = tid >> 6;
    const int lane = tid & 63;
    const int g = lane >> 4;
    const int r = lane & 15;
    const int srow = lane >> 2;   // staging: row slot this lane serves
    const int schk = lane & 3;    // staging: 16B chunk within row half

    // persistent weight fragments: xj-part of layer1 + layer2
    s16x8 axj[2][4], ab[2][4];
#pragma unroll
    for (int kc = 0; kc < 2; ++kc)
#pragma unroll
        for (int mt = 0; mt < 4; ++mt) {
            axj[kc][mt] = *(const s16x8*)(pWxj + ((kc * 4 + mt) * 64 + lane) * 8);
            ab[kc][mt] = *(const s16x8*)(pWb + ((kc * 4 + mt) * 64 + lane) * 8);
        }

    unsigned short* myx = xstage[w];
    unsigned short* myl = h1lds[w];
    const int totalWaves = gridDim.x * 4;

    for (int node = blockIdx.x * 4 + w; node < N; node += totalWaves) {
        const int segB = offsets[node];
        const int segE = offsets[node + 1];

        f32x4 rm[4];
#pragma unroll
        for (int mt = 0; mt < 4; ++mt)
            rm[mt] = (f32x4){-INFINITY, -INFINITY, -INFINITY, -INFINITY};

        if (segB < segE) {
            // xi-part + bias, once per node (broadcast across the 16 columns)
            s16x8 xi1 = *(const s16x8*)(xb + node * 64 + g * 8);
            s16x8 xi2 = *(const s16x8*)(xb + node * 64 + 32 + g * 8);
            f32x4 accxi[4];
#pragma unroll
            for (int mt = 0; mt < 4; ++mt)
                accxi[mt] = *(const f32x4*)(ba + mt * 16 + g * 4);
#pragma unroll
            for (int mt = 0; mt < 4; ++mt) {
                s16x8 f0 = *(const s16x8*)(pWxi + ((0 * 4 + mt) * 64 + lane) * 8);
                accxi[mt] = __builtin_amdgcn_mfma_f32_16x16x32_bf16(f0, xi1, accxi[mt], 0, 0, 0);
                s16x8 f1 = *(const s16x8*)(pWxi + ((1 * 4 + mt) * 64 + lane) * 8);
                accxi[mt] = __builtin_amdgcn_mfma_f32_16x16x32_bf16(f1, xi2, accxi[mt], 0, 0, 0);
            }

            for (int t0 = segB; t0 < segE; t0 += 16) {
                // coalesced gather: 4 adjacent lanes load one 64B span of a row
                int sidx = min(t0 + srow, segE - 1);
                int s = ssrc[sidx];
                s16x8 ra = *(const s16x8*)(xb + s * 64 + schk * 8);
                s16x8 rb = *(const s16x8*)(xb + s * 64 + 32 + schk * 8);
                *(s16x8*)(myx + srow * 72 + schk * 8) = ra;
                *(s16x8*)(myx + srow * 72 + 32 + schk * 8) = rb;
                // per-wave LDS: lockstep, no barrier needed
                s16x8 xj1 = *(const s16x8*)(myx + r * 72 + g * 8);
                s16x8 xj2 = *(const s16x8*)(myx + r * 72 + 32 + g * 8);

                f32x4 acc[4];
#pragma unroll
                for (int mt = 0; mt < 4; ++mt) acc[mt] = accxi[mt];
#pragma unroll
                for (int mt = 0; mt < 4; ++mt) {
                    acc[mt] = __builtin_amdgcn_mfma_f32_16x16x32_bf16(axj[0][mt], xj1, acc[mt], 0, 0, 0);
                    acc[mt] = __builtin_amdgcn_mfma_f32_16x16x32_bf16(axj[1][mt], xj2, acc[mt], 0, 0, 0);
                }

                // relu + pack h1 row (bf16) to per-wave LDS
#pragma unroll
                for (int mt = 0; mt < 4; ++mt) {
                    float v0 = fmaxf(acc[mt][0], 0.f);
                    float v1 = fmaxf(acc[mt][1], 0.f);
                    float v2 = fmaxf(acc[mt][2], 0.f);
                    float v3 = fmaxf(acc[mt][3], 0.f);
                    uint2 pr;
                    pr.x = pk2(v0, v1);
                    pr.y = pk2(v2, v3);
                    *(uint2*)(myl + r * 72 + mt * 16 + g * 4) = pr;
                }

                s16x8 p0 = *(const s16x8*)(myl + r * 72 + g * 8);
                s16x8 p1 = *(const s16x8*)(myl + r * 72 + 32 + g * 8);

                f32x4 acc2[4];
#pragma unroll
                for (int mt = 0; mt < 4; ++mt) acc2[mt] = (f32x4){0.f, 0.f, 0.f, 0.f};
#pragma unroll
                for (int mt = 0; mt < 4; ++mt) {
                    acc2[mt] = __builtin_amdgcn_mfma_f32_16x16x32_bf16(ab[0][mt], p0, acc2[mt], 0, 0, 0);
                    acc2[mt] = __builtin_amdgcn_mfma_f32_16x16x32_bf16(ab[1][mt], p1, acc2[mt], 0, 0, 0);
                }

                if (t0 + r < segE) {
#pragma unroll
                    for (int mt = 0; mt < 4; ++mt)
#pragma unroll
                        for (int q = 0; q < 4; ++q)
                            rm[mt][q] = fmaxf(rm[mt][q], acc2[mt][q]);
                }
            }
        }

        // butterfly max across the 16 edge-columns
#pragma unroll
        for (int mt = 0; mt < 4; ++mt)
#pragma unroll
            for (int q = 0; q < 4; ++q) {
                float v = rm[mt][q];
                v = fmaxf(v, __shfl_xor(v, 1, 64));
                v = fmaxf(v, __shfl_xor(v, 2, 64));
                v = fmaxf(v, __shfl_xor(v, 4, 64));
                v = fmaxf(v, __shfl_xor(v, 8, 64));
                rm[mt][q] = v;
            }

        if (r == 0) {
#pragma unroll
            for (int mt = 0; mt < 4; ++mt) {
                f32x4 b2 = *(const f32x4*)(bb + mt * 16 + g * 4);
                f32x4 o;
#pragma unroll
                for (int q = 0; q < 4; ++q) o[q] = fmaxf(rm[mt][q] + b2[q], 0.f);
                *(f32x4*)(out + node * 64 + mt * 16 + g * 4) = o;
            }
        }
    }
}

// ---------------- batchnorm stats: per-channel sum & sumsq ----------------
__global__ void bn_stats(const float* __restrict__ in, float* __restrict__ stats, int N) {
    __shared__ float ls[4][64];
    __shared__ float lss[4][64];
    int c = threadIdx.x & 63;
    int rg = threadIdx.x >> 6;
    float s = 0.f, ss = 0.f;
    for (int row = blockIdx.x * 4 + rg; row < N; row += gridDim.x * 4) {
        float v = in[row * 64 + c];
        s += v;
        ss += v * v;
    }
    ls[rg][c] = s;
    lss[rg][c] = ss;
    __syncthreads();
    if (rg == 0) {
        s = ls[0][c] + ls[1][c] + ls[2][c] + ls[3][c];
        ss = lss[0][c] + lss[1][c] + lss[2][c] + lss[3][c];
        atomicAdd(&stats[c], s);
        atomicAdd(&stats[64 + c], ss);
    }
}

// ---------------- batchnorm apply (optionally emit bf16 table for next layer) ----------------
__global__ void bn_apply(const float* __restrict__ in, const float* __restrict__ stats,
                         const float* __restrict__ gamma, const float* __restrict__ beta,
                         unsigned short* __restrict__ outb, float* __restrict__ outf,
                         int n4, float invN) {
    int i = blockIdx.x * 256 + threadIdx.x;
    if (i >= n4) return;
    int c0 = (i * 4) & 63;
    f32x4 v = ((const f32x4*)in)[i];
    f32x4 o;
#pragma unroll
    for (int q = 0; q < 4; ++q) {
        int c = c0 + q;
        float mean = stats[c] * invN;
        float var = stats[64 + c] * invN - mean * mean;
        float sc = gamma[c] * rsqrtf(var + EPS);
        o[q] = (v[q] - mean) * sc + beta[c];
    }
    if (outb) {
        uint2 pr;
        pr.x = pk2(o[0], o[1]);
        pr.y = pk2(o[2], o[3]);
        *(uint2*)(outb + i * 4) = pr;
    } else {
        ((f32x4*)outf)[i] = o;
    }
}

extern "C" void kernel_launch(void* const* d_in, const int* in_sizes, int n_in,
                              void* d_out, int out_size, void* d_ws, size_t ws_size,
                              hipStream_t stream) {
    const float* x = (const float*)d_in[0];
    const int* ei = (const int*)d_in[1];
    // d_in[2] = batch (unused, single graph)
    const float* W1a = (const float*)d_in[3];
    const float* b1a = (const float*)d_in[4];
    const float* W1b = (const float*)d_in[5];
    const float* b1b = (const float*)d_in[6];
    const float* gamma1 = (const float*)d_in[7];
    const float* beta1 = (const float*)d_in[8];
    const float* W2a = (const float*)d_in[9];
    const float* b2a = (const float*)d_in[10];
    const float* W2b = (const float*)d_in[11];
    const float* b2b = (const float*)d_in[12];
    const float* gamma2 = (const float*)d_in[13];
    const float* beta2 = (const float*)d_in[14];

    const int N = in_sizes[0] / 64;
    const int E = in_sizes[1] / 2;
    const int NC = N * 64;

    char* ws = (char*)d_ws;
    size_t off = 0;
    auto alloc = [&](size_t bytes) {
        char* p = ws + off;
        off += (bytes + 255) & ~(size_t)255;
        return p;
    };
    float* acc = (float*)alloc((size_t)NC * 4);                   // layer-1 pre-BN output
    unsigned short* xb = (unsigned short*)alloc((size_t)NC * 2);  // bf16 feature table
    unsigned short* pw = (unsigned short*)alloc(24576 * 2);
    float* stats = (float*)alloc(256 * 4);
    int* count = (int*)alloc((size_t)N * 4);
    int* offsets = (int*)alloc((size_t)(N + 1) * 4);
    int* cursor = (int*)alloc((size_t)(N + 1) * 4);
    int* ssrc = (int*)alloc((size_t)E * 4);
    int* bsums = (int*)alloc(1024 * 4);

    const int* esrc = ei;
    const int* edst = ei + E;

    // pack weights + zero stats/count
    int pgrid = (24832 + N + 255) / 256;
    pack_all<<<pgrid, 256, 0, stream>>>(W1a, W1b, W2a, W2b, pw, stats, count, N);

    // bf16 table + dst histogram
    int n4 = NC / 4;
    int big = max(n4, E);
    cvt_hist<<<(big + 255) / 256, 256, 0, stream>>>(x, xb, n4, edst, count, E);

    // two-level scan (counting sort offsets)
    int nb = (N + 1023) / 1024;
    scan1<<<nb, 256, 0, stream>>>(count, offsets, bsums, N);
    scan2<<<1, 256, 0, stream>>>(bsums, offsets, N, nb);
    scan3<<<(N + 255) / 256, 256, 0, stream>>>(offsets, cursor, bsums, N);
    scatter_kernel<<<(E + 255) / 256, 256, 0, stream>>>(esrc, edst, cursor, ssrc, E);

    int cgrid = (n4 + 255) / 256;
    int egrid = (N + 7) / 8;  // 2 nodes per wave

    // layer 1
    edgeconv_sorted<<<egrid, 256, 0, stream>>>(xb, ssrc, offsets, pw, pw + 4096, pw + 8192,
                                               b1a, b1b, acc, N);
    bn_stats<<<512, 256, 0, stream>>>(acc, stats, N);
    bn_apply<<<cgrid, 256, 0, stream>>>(acc, stats, gamma1, beta1, xb, nullptr, n4, 1.0f / N);

    // layer 2
    edgeconv_sorted<<<egrid, 256, 0, stream>>>(xb, ssrc, offsets, pw + 12288, pw + 16384,
                                               pw + 20480, b2a, b2b, (float*)d_out, N);
    bn_stats<<<512, 256, 0, stream>>>((float*)d_out, stats + 128, N);
    bn_apply<<<cgrid, 256, 0, stream>>>((float*)d_out, stats + 128, gamma2, beta2, nullptr,
                                        (float*)d_out, n4, 1.0f / N);
}